// Round 1
// baseline (1238.923 us; speedup 1.0000x reference)
//
#include <hip/hip_runtime.h>

typedef __attribute__((ext_vector_type(8))) short short8;
typedef __attribute__((ext_vector_type(4))) float f32x4;

#define LOG2E 1.4426950408889634f
#define LN2   0.6931471805599453f

__device__ __forceinline__ unsigned short f2bf(float f) {
    union { float f; unsigned u; } v; v.f = f;
    unsigned u = v.u;
    u += 0x7fffu + ((u >> 16) & 1u);   // round-to-nearest-even (values are finite)
    return (unsigned short)(u >> 16);
}
__device__ __forceinline__ float bf2f(unsigned short h) {
    union { unsigned u; float f; } v; v.u = ((unsigned)h) << 16;
    return v.f;
}

// ---------------------------------------------------------------------------
// Prologue: pack W1/W2 (256x256 fp32 row-major, W[k*256+n]) into bf16 MFMA
// B-fragment order for v_mfma_f32_16x16x32_bf16:
//   lane holds B[k = ks*32 + (lane>>4)*8 + j][n = ntile*16 + (lane&15)], j=0..7
//   packed elem index = (((ntile*8 + ks)*64 + lane)*8 + j) within each layer.
// Also precompute negc[l][n] = -log2(e) / (2*sigma_l[n]^2).
// ---------------------------------------------------------------------------
__global__ void pack_kernel(const float* __restrict__ W1, const float* __restrict__ W2,
                            const float* __restrict__ s0, const float* __restrict__ s1,
                            const float* __restrict__ s2,
                            unsigned short* __restrict__ wp, float* __restrict__ negc) {
    int tid = blockIdx.x * 256 + threadIdx.x;   // 0 .. 131071
    if (tid < 131072) {
        int e = tid & 65535;
        int j = e & 7, lane = (e >> 3) & 63, ks = (e >> 9) & 7, ntile = e >> 12;
        int k = ks * 32 + ((lane >> 4) * 8) + j;
        int n = ntile * 16 + (lane & 15);
        const float* W = (tid >> 16) ? W2 : W1;
        wp[tid] = f2bf(W[k * 256 + n]);
    }
    if (tid < 768) {
        const float* s = (tid < 256) ? s0 : (tid < 512 ? s1 : s2);
        float sv = s[tid & 255];
        negc[tid] = -LOG2E / (2.0f * sv * sv);
    }
}

// ---------------------------------------------------------------------------
// Fused MLP kernel. 512 threads = 8 waves; block handles ROWS=64 rows.
// Wave w owns output columns [w*32, w*32+32) of layers 2 and 3; its W1/W2
// slices (64 VGPRs each) are preloaded once from the packed buffer.
// h lives in one padded LDS buffer (stride 264 bf16 -> 2-way bank alias, free).
// ---------------------------------------------------------------------------
constexpr int ROWS = 64;
constexpr int HSTR = 264;   // 256 + 8 pad (bf16 elems); row stride 528 B

__device__ __forceinline__ void gemm_layer(unsigned short* h, const short8 (&wf)[8][2],
                                           float bias0, float bias1, float nc0, float nc1,
                                           int lane, int col0, int col1) {
    f32x4 acc[4][2];
#pragma unroll
    for (int rg = 0; rg < 4; ++rg) {
        acc[rg][0] = f32x4{bias0, bias0, bias0, bias0};
        acc[rg][1] = f32x4{bias1, bias1, bias1, bias1};
    }
    // A-fragment base: A[m = lane&15][k = (lane>>4)*8 + j]
    const unsigned short* abase = h + (lane & 15) * HSTR + ((lane >> 4) * 8);
#pragma unroll
    for (int rg = 0; rg < 4; ++rg) {
#pragma unroll
        for (int ks = 0; ks < 8; ++ks) {
            short8 a = *(const short8*)(abase + rg * 16 * HSTR + ks * 32);
            acc[rg][0] = __builtin_amdgcn_mfma_f32_16x16x32_bf16(a, wf[ks][0], acc[rg][0], 0, 0, 0);
            acc[rg][1] = __builtin_amdgcn_mfma_f32_16x16x32_bf16(a, wf[ks][1], acc[rg][1], 0, 0, 0);
        }
    }
    __syncthreads();   // everyone done reading h before we overwrite it
    // C-layout: col = lane&15 (+ntile*16), row = rg*16 + (lane>>4)*4 + reg
#pragma unroll
    for (int rg = 0; rg < 4; ++rg) {
        int rbase = rg * 16 + (lane >> 4) * 4;
#pragma unroll
        for (int rr = 0; rr < 4; ++rr) {
            float x0 = acc[rg][0][rr];
            float x1 = acc[rg][1][rr];
            h[(rbase + rr) * HSTR + col0] = f2bf(exp2f(x0 * x0 * nc0));
            h[(rbase + rr) * HSTR + col1] = f2bf(exp2f(x1 * x1 * nc1));
        }
    }
    __syncthreads();
}

__global__ __launch_bounds__(512, 2) void mlp_kernel(
    const float* __restrict__ pos,
    const float* __restrict__ W0, const float* __restrict__ b0,
    const float* __restrict__ b1, const float* __restrict__ b2,
    const float* __restrict__ W3, const float* __restrict__ b3,
    const unsigned short* __restrict__ W1p, const unsigned short* __restrict__ W2p,
    const float* __restrict__ negc,
    float* __restrict__ out)
{
    __shared__ unsigned short h[ROWS * HSTR];   // 33792 B

    const int tid  = threadIdx.x;
    const int lane = tid & 63;
    const int wave = tid >> 6;
    const long row0 = (long)blockIdx.x * ROWS;

    // ---- preload weight B-fragments for this wave's 32 columns ----
    short8 w1f[8][2], w2f[8][2];
    {
        const short8* p1 = (const short8*)W1p;
        const short8* p2 = (const short8*)W2p;
        int nt0 = wave * 2;
#pragma unroll
        for (int t = 0; t < 2; ++t)
#pragma unroll
            for (int ks = 0; ks < 8; ++ks) {
                int idx = ((nt0 + t) * 8 + ks) * 64 + lane;
                w1f[ks][t] = p1[idx];
                w2f[ks][t] = p2[idx];
            }
    }
    const int col0 = wave * 32 + (lane & 15);
    const int col1 = col0 + 16;

    // ---- phase 0: layer 1 (K=3, fp32 vector) -> h ----
    {
        int r = tid >> 3, q = tid & 7;
        long grow = row0 + r;
        float p0 = pos[grow * 3 + 0];
        float p1 = pos[grow * 3 + 1];
        float p2 = pos[grow * 3 + 2];
#pragma unroll 4
        for (int i = 0; i < 32; ++i) {
            int n = q * 32 + i;
            float x = fmaf(p0, W0[n], fmaf(p1, W0[256 + n], fmaf(p2, W0[512 + n], b0[n])));
            h[r * HSTR + n] = f2bf(exp2f(x * x * negc[n]));
        }
    }
    __syncthreads();

    // ---- phase 1: layer 2 ----
    gemm_layer(h, w1f, b1[col0], b1[col1], negc[256 + col0], negc[256 + col1],
               lane, col0, col1);
    // ---- phase 2: layer 3 ----
    gemm_layer(h, w2f, b2[col0], b2[col1], negc[512 + col0], negc[512 + col1],
               lane, col0, col1);

    // ---- phase 3: layer 4 (K=256 -> 1) + softplus(beta=1, threshold=8) ----
    {
        int r = tid >> 3, q = tid & 7;
        const unsigned short* hrow = h + r * HSTR + q * 32;
        const float* w3 = W3 + q * 32;
        float s = 0.0f;
#pragma unroll
        for (int i = 0; i < 32; i += 8) {
            short8 hv = *(const short8*)(hrow + i);
#pragma unroll
            for (int jj = 0; jj < 8; ++jj)
                s = fmaf(bf2f((unsigned short)hv[jj]), w3[i + jj], s);
        }
        s += __shfl_xor(s, 1);
        s += __shfl_xor(s, 2);
        s += __shfl_xor(s, 4);
        if (q == 0) {
            float x  = s + b3[0];
            float xm = fminf(x, 8.0f);
            float e  = exp2f(xm * LOG2E);
            float sp = log2f(1.0f + e) * LN2;   // log1p(exp(min(x,8)))
            out[row0 + r] = (x > 8.0f) ? x : sp;
        }
    }
}

extern "C" void kernel_launch(void* const* d_in, const int* in_sizes, int n_in,
                              void* d_out, int out_size, void* d_ws, size_t ws_size,
                              hipStream_t stream) {
    const float* pos = (const float*)d_in[0];
    const float* W0  = (const float*)d_in[1];
    const float* b0  = (const float*)d_in[2];
    const float* W1  = (const float*)d_in[3];
    const float* b1  = (const float*)d_in[4];
    const float* W2  = (const float*)d_in[5];
    const float* b2  = (const float*)d_in[6];
    const float* W3  = (const float*)d_in[7];
    const float* b3  = (const float*)d_in[8];
    const float* s0  = (const float*)d_in[9];
    const float* s1  = (const float*)d_in[10];
    const float* s2  = (const float*)d_in[11];

    unsigned short* wp = (unsigned short*)d_ws;              // 131072 bf16 = 256 KB
    float* negc = (float*)((char*)d_ws + 262144);            // 3*256 fp32

    pack_kernel<<<512, 256, 0, stream>>>(W1, W2, s0, s1, s2, wp, negc);

    int nrows = in_sizes[0] / 3;          // 1048576
    int nblk  = nrows / ROWS;             // 16384
    mlp_kernel<<<nblk, 512, 0, stream>>>(pos, W0, b0, b1, b2, W3, b3,
                                         wp, wp + 65536, negc, (float*)d_out);
}

// Round 2
// 482.348 us; speedup vs baseline: 2.5685x; 2.5685x over previous
//
#include <hip/hip_runtime.h>

typedef __attribute__((ext_vector_type(8))) short short8;
typedef __attribute__((ext_vector_type(4))) float f32x4;
typedef __attribute__((ext_vector_type(2))) unsigned int uint2v;

#define LOG2E 1.4426950408889634f
#define LN2   0.6931471805599453f

__device__ __forceinline__ unsigned short f2bf(float f) {
    union { float f; unsigned u; } v; v.f = f;
    unsigned u = v.u;
    u += 0x7fffu + ((u >> 16) & 1u);   // RNE (values finite)
    return (unsigned short)(u >> 16);
}
__device__ __forceinline__ float bf2f(unsigned short h) {
    union { unsigned u; float f; } v; v.u = ((unsigned)h) << 16;
    return v.f;
}

// ---------------------------------------------------------------------------
// Prologue: pack W1/W2 into bf16 MFMA B-fragment order (16x16x32):
//   lane holds B[k = ks*32 + (lane>>4)*8 + j][n = ntile*16 + (lane&15)], j=0..7
// negc[l*256+n] = -log2(e) / (2*sigma_l[n]^2).
// ---------------------------------------------------------------------------
__global__ void pack_kernel(const float* __restrict__ W1, const float* __restrict__ W2,
                            const float* __restrict__ s0, const float* __restrict__ s1,
                            const float* __restrict__ s2,
                            unsigned short* __restrict__ wp, float* __restrict__ negc) {
    int tid = blockIdx.x * 256 + threadIdx.x;   // 0 .. 131071
    if (tid < 131072) {
        int e = tid & 65535;
        int j = e & 7, lane = (e >> 3) & 63, ks = (e >> 9) & 7, ntile = e >> 12;
        int k = ks * 32 + ((lane >> 4) * 8) + j;
        int n = ntile * 16 + (lane & 15);
        const float* W = (tid >> 16) ? W2 : W1;
        wp[tid] = f2bf(W[k * 256 + n]);
    }
    if (tid < 768) {
        const float* s = (tid < 256) ? s0 : (tid < 512 ? s1 : s2);
        float sv = s[tid & 255];
        negc[tid] = -LOG2E / (2.0f * sv * sv);
    }
}

constexpr int ROWS = 64;
constexpr int HSTR = 264;   // 256 + 8 pad bf16 elems; row stride 528 B

// One GEMM layer: wave owns ntiles (2w, 2w+1) = cols [w*32, w*32+32).
// Weights loaded from packed global (L1/L2-hot) at layer start: 64 VGPRs live.
__device__ __forceinline__ void gemm_layer(unsigned short* __restrict__ h,
                                           const unsigned short* __restrict__ wpk,
                                           const float* __restrict__ bias,
                                           const float* __restrict__ ncp,
                                           int lane, int wave) {
    short8 wf[8][2];
    {
        const short8* p = (const short8*)wpk;
        int nt0 = wave * 2;
#pragma unroll
        for (int t = 0; t < 2; ++t)
#pragma unroll
            for (int ks = 0; ks < 8; ++ks)
                wf[ks][t] = p[((nt0 + t) * 8 + ks) * 64 + lane];
    }
    const int col0 = wave * 32 + (lane & 15);
    const int col1 = col0 + 16;
    const float bias0 = bias[col0], bias1 = bias[col1];
    const float nc0 = ncp[col0], nc1 = ncp[col1];

    f32x4 acc[4][2];
#pragma unroll
    for (int rg = 0; rg < 4; ++rg) {
        acc[rg][0] = f32x4{bias0, bias0, bias0, bias0};
        acc[rg][1] = f32x4{bias1, bias1, bias1, bias1};
    }
    const unsigned short* abase = h + (lane & 15) * HSTR + ((lane >> 4) * 8);
#pragma unroll
    for (int rg = 0; rg < 4; ++rg) {
#pragma unroll
        for (int ks = 0; ks < 8; ++ks) {
            short8 a = *(const short8*)(abase + rg * 16 * HSTR + ks * 32);
            acc[rg][0] = __builtin_amdgcn_mfma_f32_16x16x32_bf16(a, wf[ks][0], acc[rg][0], 0, 0, 0);
            acc[rg][1] = __builtin_amdgcn_mfma_f32_16x16x32_bf16(a, wf[ks][1], acc[rg][1], 0, 0, 0);
        }
    }
    __syncthreads();   // all reads of h done before overwrite

    // Activation; DPP pair-pack (lanes 2k/2k+1 hold adjacent cols) -> b32 writes.
    const int sel = lane & 1;
#pragma unroll
    for (int rg = 0; rg < 4; ++rg) {
        int rbase = rg * 16 + ((lane >> 4) & 3) * 4;
#pragma unroll
        for (int rr = 0; rr < 4; ++rr) {
            float x0 = acc[rg][0][rr];
            float x1 = acc[rg][1][rr];
            unsigned p = (unsigned)f2bf(__builtin_amdgcn_exp2f(x0 * x0 * nc0)) |
                         ((unsigned)f2bf(__builtin_amdgcn_exp2f(x1 * x1 * nc1)) << 16);
            unsigned q = (unsigned)__builtin_amdgcn_mov_dpp((int)p, 177 /*quad_perm[1,0,3,2]*/,
                                                            0xf, 0xf, true);
            unsigned val = sel ? ((q >> 16) | (p & 0xffff0000u))
                               : ((p & 0xffffu) | (q << 16));
            int col = sel ? (col1 - 1) : col0;       // even in both cases
            *(unsigned*)&h[(rbase + rr) * HSTR + col] = val;
        }
    }
    __syncthreads();
}

__global__ __launch_bounds__(512, 4) void mlp_kernel(
    const float* __restrict__ pos,
    const float* __restrict__ W0, const float* __restrict__ b0,
    const float* __restrict__ b1, const float* __restrict__ b2,
    const float* __restrict__ W3, const float* __restrict__ b3,
    const unsigned short* __restrict__ W1p, const unsigned short* __restrict__ W2p,
    const float* __restrict__ negc,
    float* __restrict__ out)
{
    __shared__ unsigned short h[ROWS * HSTR];   // 33792 B
    __shared__ float posS[ROWS * 3];            // 768 B

    const int tid  = threadIdx.x;
    const int lane = tid & 63;
    const int wave = tid >> 6;
    const long row0 = (long)blockIdx.x * ROWS;

    // ---- stage pos (coalesced) ----
    if (tid < ROWS * 3) posS[tid] = pos[row0 * 3 + tid];
    __syncthreads();

    // ---- layer 1 (K=3): wave w rows [w*8,w*8+8), lane owns cols 4L..4L+3 ----
    {
        const int n0 = lane * 4;
        f32x4 w0x = *(const f32x4*)(W0 + n0);
        f32x4 w0y = *(const f32x4*)(W0 + 256 + n0);
        f32x4 w0z = *(const f32x4*)(W0 + 512 + n0);
        f32x4 bb  = *(const f32x4*)(b0 + n0);
        f32x4 nc  = *(const f32x4*)(negc + n0);
        const int rbase = wave * 8;
#pragma unroll
        for (int j = 0; j < 8; ++j) {
            float p0 = posS[(rbase + j) * 3 + 0];
            float p1 = posS[(rbase + j) * 3 + 1];
            float p2 = posS[(rbase + j) * 3 + 2];
            float a0 = __builtin_amdgcn_exp2f([&]{float x=fmaf(p0,w0x[0],fmaf(p1,w0y[0],fmaf(p2,w0z[0],bb[0])));return x*x*nc[0];}());
            float a1 = __builtin_amdgcn_exp2f([&]{float x=fmaf(p0,w0x[1],fmaf(p1,w0y[1],fmaf(p2,w0z[1],bb[1])));return x*x*nc[1];}());
            float a2 = __builtin_amdgcn_exp2f([&]{float x=fmaf(p0,w0x[2],fmaf(p1,w0y[2],fmaf(p2,w0z[2],bb[2])));return x*x*nc[2];}());
            float a3 = __builtin_amdgcn_exp2f([&]{float x=fmaf(p0,w0x[3],fmaf(p1,w0y[3],fmaf(p2,w0z[3],bb[3])));return x*x*nc[3];}());
            uint2v v;
            v[0] = (unsigned)f2bf(a0) | ((unsigned)f2bf(a1) << 16);
            v[1] = (unsigned)f2bf(a2) | ((unsigned)f2bf(a3) << 16);
            *(uint2v*)&h[(rbase + j) * HSTR + n0] = v;
        }
    }
    __syncthreads();

    // ---- layers 2 & 3 (MFMA) ----
    gemm_layer(h, W1p, b1, negc + 256, lane, wave);
    gemm_layer(h, W2p, b2, negc + 512, lane, wave);

    // ---- layer 4 (K=256 -> 1) + softplus(beta=1, threshold=8) ----
    {
        int r = tid >> 3, q = tid & 7;
        const unsigned short* hrow = h + r * HSTR + q * 32;
        const float* w3 = W3 + q * 32;
        float s = 0.0f;
#pragma unroll
        for (int i = 0; i < 32; i += 8) {
            short8 hv = *(const short8*)(hrow + i);
            f32x4 wA = *(const f32x4*)(w3 + i);
            f32x4 wB = *(const f32x4*)(w3 + i + 4);
#pragma unroll
            for (int jj = 0; jj < 4; ++jj) {
                s = fmaf(bf2f((unsigned short)hv[jj]), wA[jj], s);
                s = fmaf(bf2f((unsigned short)hv[4 + jj]), wB[jj], s);
            }
        }
        s += __shfl_xor(s, 1);
        s += __shfl_xor(s, 2);
        s += __shfl_xor(s, 4);
        if (q == 0) {
            float x  = s + b3[0];
            float xm = fminf(x, 8.0f);
            float e  = __builtin_amdgcn_exp2f(xm * LOG2E);
            float sp = __builtin_amdgcn_logf(1.0f + e) * LN2;   // log1p(exp(min(x,8)))
            out[row0 + r] = (x > 8.0f) ? x : sp;
        }
    }
}

extern "C" void kernel_launch(void* const* d_in, const int* in_sizes, int n_in,
                              void* d_out, int out_size, void* d_ws, size_t ws_size,
                              hipStream_t stream) {
    const float* pos = (const float*)d_in[0];
    const float* W0  = (const float*)d_in[1];
    const float* b0  = (const float*)d_in[2];
    const float* W1  = (const float*)d_in[3];
    const float* b1  = (const float*)d_in[4];
    const float* W2  = (const float*)d_in[5];
    const float* b2  = (const float*)d_in[6];
    const float* W3  = (const float*)d_in[7];
    const float* b3  = (const float*)d_in[8];
    const float* s0  = (const float*)d_in[9];
    const float* s1  = (const float*)d_in[10];
    const float* s2  = (const float*)d_in[11];

    unsigned short* wp = (unsigned short*)d_ws;              // 131072 bf16 = 256 KB
    float* negc = (float*)((char*)d_ws + 262144);            // 3*256 fp32

    pack_kernel<<<512, 256, 0, stream>>>(W1, W2, s0, s1, s2, wp, negc);

    int nrows = in_sizes[0] / 3;          // 1048576
    int nblk  = nrows / ROWS;             // 16384
    mlp_kernel<<<nblk, 512, 0, stream>>>(pos, W0, b0, b1, b2, W3, b3,
                                         wp, wp + 65536, negc, (float*)d_out);
}

// Round 3
// 466.152 us; speedup vs baseline: 2.6578x; 1.0347x over previous
//
#include <hip/hip_runtime.h>
#include <hip/hip_bf16.h>

typedef __attribute__((ext_vector_type(8))) short short8;
typedef __attribute__((ext_vector_type(4))) float f32x4;

#define LOG2E 1.4426950408889634f
#define LN2   0.6931471805599453f

__device__ __forceinline__ unsigned short f2bf(float f) {
    union { float f; unsigned u; } v; v.f = f;
    unsigned u = v.u;
    u += 0x7fffu + ((u >> 16) & 1u);   // RNE, finite values
    return (unsigned short)(u >> 16);
}
__device__ __forceinline__ float bf2f(unsigned short h) {
    union { unsigned u; float f; } v; v.u = ((unsigned)h) << 16;
    return v.f;
}
__device__ __forceinline__ unsigned pk_bf16(float a, float b) {
    __hip_bfloat162 t = __float22bfloat162_rn(float2{a, b});   // v_cvt_pk_bf16_f32
    union { __hip_bfloat162 b; unsigned u; } v; v.b = t;
    return v.u;
}

// ---------------------------------------------------------------------------
// Pack: W0 (hi/lo split, K=9 padded to 32, 16 tiles x 512), W1, W2 (16 tiles
// x 8 ks x 512) into 16x16x32 B-frag order with PAIR PERMUTATION:
//   tile t, frag col i -> phys col (t>>1)*32 + 2*i + (t&1)
// so tiles (2p, 2p+1) give each lane adjacent phys cols -> b32 packed writes.
// negc[l*256+n] = -log2(e)/(2*sigma^2).
// ---------------------------------------------------------------------------
__global__ void pack_kernel(const float* __restrict__ W0, const float* __restrict__ W1,
                            const float* __restrict__ W2,
                            const float* __restrict__ s0, const float* __restrict__ s1,
                            const float* __restrict__ s2,
                            unsigned short* __restrict__ wp, float* __restrict__ negc) {
    int tid = blockIdx.x * 256 + threadIdx.x;    // 0 .. 139263
    if (tid < 8192) {                            // W0 pack: A rows [ph,ph,pl]/dim, B rows [wh,wl,wh]/dim
        int j = tid & 7, lane = (tid >> 3) & 63, t = tid >> 9;
        int k = ((lane >> 4) * 8) + j;           // 0..31
        int n = ((t >> 1) * 32) + 2 * (lane & 15) + (t & 1);
        unsigned short v = 0;
        if (k < 9) {
            int d = k / 3, m = k - d * 3;        // m: 0->wh 1->wl 2->wh
            float w = W0[d * 256 + n];
            unsigned short wh = f2bf(w);
            v = (m == 1) ? f2bf(w - bf2f(wh)) : wh;
        }
        wp[tid] = v;
    } else if (tid < 139264) {
        int e = tid - 8192;
        const float* W = W1;
        if (e >= 65536) { W = W2; e -= 65536; }
        int j = e & 7, lane = (e >> 3) & 63, ks = (e >> 9) & 7, t = e >> 12;
        int k = ks * 32 + ((lane >> 4) * 8) + j;
        int n = ((t >> 1) * 32) + 2 * (lane & 15) + (t & 1);
        wp[tid] = f2bf(W[k * 256 + n]);
    }
    if (tid < 768) {
        const float* s = (tid < 256) ? s0 : (tid < 512 ? s1 : s2);
        float sv = s[tid & 255];
        negc[tid] = -LOG2E / (2.0f * sv * sv);
    }
}

constexpr int ROWS = 128;
constexpr int HSTR = 264;    // bf16 elems/row (+8 pad)

// One MFMA layer. Wave = (half = wave>>2) row-half x (cq = wave&3) col-quarter.
// Tiles cq*4 + nt; pair permutation makes (nt even, nt odd) adjacent phys cols.
template <int NKS, int SSTR>
__device__ __forceinline__ void layer(const unsigned short* __restrict__ src,
                                      const unsigned short* __restrict__ wpk,
                                      const float* __restrict__ bias,
                                      const float* __restrict__ ncp,
                                      unsigned short* __restrict__ hdst,
                                      int half, int cq, int i16, int q, bool presync) {
    float2 bp[2], np[2];
#pragma unroll
    for (int p = 0; p < 2; ++p) {
        int ce = cq * 64 + p * 32 + 2 * i16;
        bp[p] = *(const float2*)(bias + ce);
        np[p] = *(const float2*)(ncp + ce);
    }
    f32x4 acc[4][4];
#pragma unroll
    for (int rg = 0; rg < 4; ++rg)
#pragma unroll
        for (int nt = 0; nt < 4; ++nt) {
            float b = (nt & 1) ? bp[nt >> 1].y : bp[nt >> 1].x;
            acc[rg][nt] = f32x4{b, b, b, b};
        }
    const int lane = q * 16 + i16;
    const short8* wp8 = (const short8*)wpk;
    const unsigned short* abase = src + (half * 64 + i16) * SSTR + q * 8;
#pragma unroll
    for (int ks = 0; ks < NKS; ++ks) {
        short8 wf[4];
#pragma unroll
        for (int nt = 0; nt < 4; ++nt)
            wf[nt] = wp8[((cq * 4 + nt) * NKS + ks) * 64 + lane];
#pragma unroll
        for (int rg = 0; rg < 4; ++rg) {
            short8 a = *(const short8*)(abase + rg * 16 * SSTR + ks * 32);
#pragma unroll
            for (int nt = 0; nt < 4; ++nt)
                acc[rg][nt] = __builtin_amdgcn_mfma_f32_16x16x32_bf16(a, wf[nt], acc[rg][nt], 0, 0, 0);
        }
    }
    if (presync) __syncthreads();   // all reads of hdst done before overwrite
#pragma unroll
    for (int rg = 0; rg < 4; ++rg) {
        int row = half * 64 + rg * 16 + q * 4;
#pragma unroll
        for (int p = 0; p < 2; ++p) {
            int col = cq * 64 + p * 32 + 2 * i16;
            float ncx = np[p].x, ncy = np[p].y;
#pragma unroll
            for (int rr = 0; rr < 4; ++rr) {
                float x0 = acc[rg][2 * p][rr];
                float x1 = acc[rg][2 * p + 1][rr];
                float g0 = __builtin_amdgcn_exp2f(x0 * x0 * ncx);
                float g1 = __builtin_amdgcn_exp2f(x1 * x1 * ncy);
                *(unsigned*)&hdst[(row + rr) * HSTR + col] = pk_bf16(g0, g1);
            }
        }
    }
    __syncthreads();
}

__global__ __launch_bounds__(512, 4) void mlp_kernel(
    const float* __restrict__ pos,
    const float* __restrict__ b0, const float* __restrict__ b1,
    const float* __restrict__ b2,
    const float* __restrict__ W3, const float* __restrict__ b3,
    const unsigned short* __restrict__ Wp,
    const float* __restrict__ negc,
    float* __restrict__ out)
{
    __shared__ unsigned short h[ROWS * HSTR];   // 67584 B
    __shared__ unsigned short A0[ROWS * 32];    // 8192 B  (K=32 padded L0 A-matrix)

    const int tid  = threadIdx.x;
    const int lane = tid & 63;
    const int wave = tid >> 6;
    const int half = wave >> 2, cq = wave & 3;
    const int i16  = lane & 15, q = lane >> 4;
    const long row0 = (long)blockIdx.x * ROWS;

    // ---- build A0: row r = [p0h,p0h,p0l, p1h,p1h,p1l, p2h,p2h,p2l, 0..] ----
    if (tid < ROWS) {
        const float* pp = pos + (row0 + tid) * 3;
        float p0 = pp[0], p1 = pp[1], p2 = pp[2];
        short h0 = (short)f2bf(p0); short l0 = (short)f2bf(p0 - bf2f((unsigned short)h0));
        short h1 = (short)f2bf(p1); short l1 = (short)f2bf(p1 - bf2f((unsigned short)h1));
        short h2 = (short)f2bf(p2); short l2 = (short)f2bf(p2 - bf2f((unsigned short)h2));
        short8 s0v = short8{h0, h0, l0, h1, h1, l1, h2, h2};
        short8 s1v = short8{l2, 0, 0, 0, 0, 0, 0, 0};
        short8 zv  = short8{0, 0, 0, 0, 0, 0, 0, 0};
        unsigned short* arow = A0 + tid * 32;
        *(short8*)(arow + 0)  = s0v;
        *(short8*)(arow + 8)  = s1v;
        *(short8*)(arow + 16) = zv;
        *(short8*)(arow + 24) = zv;
    }
    __syncthreads();

    // ---- layer 0 (MFMA, K=32 incl. hi/lo), then layers 1,2 ----
    layer<1, 32>(A0, Wp, b0, negc, h, half, cq, i16, q, false);
    layer<8, HSTR>(h, Wp + 8192, b1, negc + 256, h, half, cq, i16, q, true);
    layer<8, HSTR>(h, Wp + 73728, b2, negc + 512, h, half, cq, i16, q, true);

    // ---- layer 4: dot(h_row, W3) + softplus(beta=1, thr=8) ----
    {
        int r = tid >> 2, qq = tid & 3;           // 4 threads/row, 64 cols each
        const unsigned short* hrow = h + r * HSTR + qq * 64;
        const float* w3 = W3 + qq * 64;
        float s = 0.0f;
#pragma unroll
        for (int i = 0; i < 64; i += 8) {
            short8 hv = *(const short8*)(hrow + i);
            f32x4 wA = *(const f32x4*)(w3 + i);
            f32x4 wB = *(const f32x4*)(w3 + i + 4);
#pragma unroll
            for (int jj = 0; jj < 4; ++jj) {
                s = fmaf(bf2f((unsigned short)hv[jj]), wA[jj], s);
                s = fmaf(bf2f((unsigned short)hv[4 + jj]), wB[jj], s);
            }
        }
        s += __shfl_xor(s, 1);
        s += __shfl_xor(s, 2);
        if (qq == 0) {
            float x  = s + b3[0];
            float xm = fminf(x, 8.0f);
            float e  = __builtin_amdgcn_exp2f(xm * LOG2E);
            float sp = __builtin_amdgcn_logf(1.0f + e) * LN2;
            out[row0 + r] = (x > 8.0f) ? x : sp;
        }
    }
}

extern "C" void kernel_launch(void* const* d_in, const int* in_sizes, int n_in,
                              void* d_out, int out_size, void* d_ws, size_t ws_size,
                              hipStream_t stream) {
    const float* pos = (const float*)d_in[0];
    const float* W0  = (const float*)d_in[1];
    const float* b0  = (const float*)d_in[2];
    const float* W1  = (const float*)d_in[3];
    const float* b1  = (const float*)d_in[4];
    const float* W2  = (const float*)d_in[5];
    const float* b2  = (const float*)d_in[6];
    const float* W3  = (const float*)d_in[7];
    const float* b3  = (const float*)d_in[8];
    const float* s0  = (const float*)d_in[9];
    const float* s1  = (const float*)d_in[10];
    const float* s2  = (const float*)d_in[11];

    unsigned short* wp = (unsigned short*)d_ws;              // 139264 bf16 = 278528 B
    float* negc = (float*)((char*)d_ws + 278528);            // 768 fp32

    pack_kernel<<<544, 256, 0, stream>>>(W0, W1, W2, s0, s1, s2, wp, negc);

    int nrows = in_sizes[0] / 3;          // 1048576
    int nblk  = nrows / ROWS;             // 8192
    mlp_kernel<<<nblk, 512, 0, stream>>>(pos, b0, b1, b2, W3, b3, wp, negc,
                                         (float*)d_out);
}